// Round 3
// baseline (96.091 us; speedup 1.0000x reference)
//
#include <hip/hip_runtime.h>
#include <math.h>

#define BB 48
#define SS 1024
#define KS 4                  // key slices per (combo,batch)
#define SSK (SS / KS)         // 256 keys per slice
#define NCB (3 * BB)          // 144 combo-batches
#define NROW (BB * SS)
#define QCH 2                 // query chunks (512 queries each)

// ws layout:
//   part[KS][NCB][SS][4]  (A0,A1,A2,l) partial sums   = 9,437,184 B
//   acc[18]               BN sum / sumsq              (zeroed each launch)
#define PART_FLOATS ((size_t)KS * NCB * SS * 4)

// Kernel 1: projection + no-max single-pass attention partials.
// grid = NCB*QCH*KS = 1152 blocks x 4 waves = 4608 waves -> fully co-resident
// (4.5 waves/SIMD). 2 queries/thread keeps LDS broadcast-read demand at ~30%
// of VALU issue. Q pre-scaled by 1/sqrt(3)*log2(e) so exp(s) == exp2(s').
__global__ __launch_bounds__(256) void mbfca_attn(
    const float* __restrict__ x,
    const float* __restrict__ WQ, const float* __restrict__ bQ,
    const float* __restrict__ WK, const float* __restrict__ bK,
    const float* __restrict__ WV, const float* __restrict__ bV,
    float* __restrict__ part)
{
    const int bid   = blockIdx.x;
    const int slice = bid & (KS - 1);
    const int qc    = (bid >> 2) & (QCH - 1);
    const int cb    = bid >> 3;          // 0..143
    const int c     = cb / BB;           // combo
    const int b     = cb % BB;           // batch
    const int kband = c;
    const int vband = (c + 1) % 3;
    const int qband = (c + 2) % 3;

    __shared__ __align__(16) float Ksm[3][SSK];
    __shared__ __align__(16) float Vsm[3][SSK];

    const int tid = threadIdx.x;

    // uniform weights
    float wk[9], wv[9], wq[9], bk[3], bv[3], bq[3];
    #pragma unroll
    for (int i = 0; i < 9; ++i) {
        wk[i] = WK[kband * 9 + i];
        wv[i] = WV[vband * 9 + i];
        wq[i] = WQ[qband * 9 + i];
    }
    #pragma unroll
    for (int i = 0; i < 3; ++i) {
        bk[i] = bK[kband * 3 + i];
        bv[i] = bV[vband * 3 + i];
        bq[i] = bQ[qband * 3 + i];
    }

    const float* xk = x + (size_t)(kband * BB + b) * SS * 3;
    const float* xv = x + (size_t)(vband * BB + b) * SS * 3;
    const float* xq = x + (size_t)(qband * BB + b) * SS * 3;

    // stage this slice's projected K,V (256 keys, 1 key/thread)
    {
        const int t = slice * SSK + tid;
        float a0 = xk[t * 3 + 0], a1 = xk[t * 3 + 1], a2 = xk[t * 3 + 2];
        Ksm[0][tid] = wk[0] * a0 + wk[1] * a1 + wk[2] * a2 + bk[0];
        Ksm[1][tid] = wk[3] * a0 + wk[4] * a1 + wk[5] * a2 + bk[1];
        Ksm[2][tid] = wk[6] * a0 + wk[7] * a1 + wk[8] * a2 + bk[2];
        float c0 = xv[t * 3 + 0], c1 = xv[t * 3 + 1], c2 = xv[t * 3 + 2];
        Vsm[0][tid] = wv[0] * c0 + wv[1] * c1 + wv[2] * c2 + bv[0];
        Vsm[1][tid] = wv[3] * c0 + wv[4] * c1 + wv[5] * c2 + bv[1];
        Vsm[2][tid] = wv[6] * c0 + wv[7] * c1 + wv[8] * c2 + bv[2];
    }
    __syncthreads();

    // 2 queries/thread: s = qc*512 + 2*tid + j.
    // qscale = (1/sqrt(3)) * log2(e): exp2(q'.k) == exp(q.k/sqrt(3)) exactly.
    const float qscale = 0.57735026918962576f * 1.4426950408889634f;
    float q0[QCH], q1[QCH], q2[QCH];
    {
        const float* bp = xq + (size_t)(qc * 512 + 2 * tid) * 3;  // 8B-aligned
        float2 f0 = *reinterpret_cast<const float2*>(bp + 0);
        float2 f1 = *reinterpret_cast<const float2*>(bp + 2);
        float2 f2 = *reinterpret_cast<const float2*>(bp + 4);
        float a[6] = {f0.x, f0.y, f1.x, f1.y, f2.x, f2.y};
        #pragma unroll
        for (int j = 0; j < 2; ++j) {
            float a0 = a[j * 3 + 0], a1 = a[j * 3 + 1], a2 = a[j * 3 + 2];
            q0[j] = (wq[0] * a0 + wq[1] * a1 + wq[2] * a2 + bq[0]) * qscale;
            q1[j] = (wq[3] * a0 + wq[4] * a1 + wq[5] * a2 + bq[1]) * qscale;
            q2[j] = (wq[6] * a0 + wq[7] * a1 + wq[8] * a2 + bq[2]) * qscale;
        }
    }

    float l[2]  = {0.f, 0.f};
    float A0[2] = {0.f, 0.f}, A1[2] = {0.f, 0.f}, A2[2] = {0.f, 0.f};

    const float4* K0 = reinterpret_cast<const float4*>(&Ksm[0][0]);
    const float4* K1 = reinterpret_cast<const float4*>(&Ksm[1][0]);
    const float4* K2 = reinterpret_cast<const float4*>(&Ksm[2][0]);
    const float4* V0 = reinterpret_cast<const float4*>(&Vsm[0][0]);
    const float4* V1 = reinterpret_cast<const float4*>(&Vsm[1][0]);
    const float4* V2 = reinterpret_cast<const float4*>(&Vsm[2][0]);

    for (int t4 = 0; t4 < SSK / 4; ++t4) {   // 64 iterations
        float4 k0 = K0[t4], k1 = K1[t4], k2 = K2[t4];
        float4 v0 = V0[t4], v1 = V1[t4], v2 = V2[t4];
        #pragma unroll
        for (int j = 0; j < 2; ++j) {
            float s0 = q0[j] * k0.x + q1[j] * k1.x + q2[j] * k2.x;
            float s1 = q0[j] * k0.y + q1[j] * k1.y + q2[j] * k2.y;
            float s2 = q0[j] * k0.z + q1[j] * k1.z + q2[j] * k2.z;
            float s3 = q0[j] * k0.w + q1[j] * k1.w + q2[j] * k2.w;
            float p0 = exp2f(s0);
            float p1 = exp2f(s1);
            float p2 = exp2f(s2);
            float p3 = exp2f(s3);
            l[j]  += (p0 + p1) + (p2 + p3);
            A0[j] += p0 * v0.x + p1 * v0.y + p2 * v0.z + p3 * v0.w;
            A1[j] += p0 * v1.x + p1 * v1.y + p2 * v1.z + p3 * v1.w;
            A2[j] += p0 * v2.x + p1 * v2.y + p2 * v2.z + p3 * v2.w;
        }
    }

    // deterministic per-slice store: part[slice][cb][s] = (A0,A1,A2,l)
    float4* dst = reinterpret_cast<float4*>(part) +
                  ((size_t)(slice * NCB + cb) * SS + qc * 512 + 2 * tid);
    dst[0] = make_float4(A0[0], A1[0], A2[0], l[0]);
    dst[1] = make_float4(A0[1], A1[1], A2[1], l[1]);
}

// Kernel 2: reduce slices -> attention out (on the fly), BN sum/sumsq
// partials -> 18 atomics/block.
__global__ __launch_bounds__(256) void mbfca_stats(
    const float* __restrict__ part, float* __restrict__ acc)
{
    const int r = blockIdx.x * 256 + threadIdx.x;   // row 0..49151
    const int b = r >> 10, s = r & 1023;
    __shared__ float red[4][18];

    float sums[18];
    #pragma unroll
    for (int k = 0; k < 18; ++k) sums[k] = 0.f;

    const float4* p4 = reinterpret_cast<const float4*>(part);
    #pragma unroll
    for (int c = 0; c < 3; ++c) {
        const int cb = c * BB + b;
        float4 t = make_float4(0.f, 0.f, 0.f, 0.f);
        #pragma unroll
        for (int sl = 0; sl < KS; ++sl) {
            float4 u = p4[(size_t)(sl * NCB + cb) * SS + s];
            t.x += u.x; t.y += u.y; t.z += u.z; t.w += u.w;
        }
        float inv = 1.0f / t.w;
        float o0 = t.x * inv, o1 = t.y * inv, o2 = t.z * inv;
        sums[3 * c + 0] = o0;          sums[3 * c + 1] = o1;          sums[3 * c + 2] = o2;
        sums[9 + 3 * c + 0] = o0 * o0; sums[9 + 3 * c + 1] = o1 * o1; sums[9 + 3 * c + 2] = o2 * o2;
    }

    #pragma unroll
    for (int off = 32; off >= 1; off >>= 1)
        #pragma unroll
        for (int k = 0; k < 18; ++k)
            sums[k] += __shfl_xor(sums[k], off, 64);

    const int tid = threadIdx.x;
    if ((tid & 63) == 0) {
        #pragma unroll
        for (int k = 0; k < 18; ++k) red[tid >> 6][k] = sums[k];
    }
    __syncthreads();
    if (tid < 18)
        atomicAdd(&acc[tid], red[0][tid] + red[1][tid] + red[2][tid] + red[3][tid]);
}

// Kernel 3: recompute attention out from slices, apply BN + FC, write y.
__global__ __launch_bounds__(256) void mbfca_bnfc(
    const float* __restrict__ part, const float* __restrict__ acc,
    const float* __restrict__ gamma, const float* __restrict__ beta,
    const float* __restrict__ fcw, const float* __restrict__ fcb,
    float* __restrict__ out)
{
    const int r = blockIdx.x * 256 + threadIdx.x;
    const int b = r >> 10, s = r & 1023;
    const float invN = 1.0f / (float)NROW;

    float sc[9], sh[9];
    #pragma unroll
    for (int ch = 0; ch < 9; ++ch) {
        float mean = acc[ch] * invN;
        float var  = acc[9 + ch] * invN - mean * mean;  // biased variance
        float sfac = gamma[ch] * rsqrtf(var + 1e-5f);
        sc[ch] = sfac;
        sh[ch] = beta[ch] - mean * sfac;
    }

    const float4* p4 = reinterpret_cast<const float4*>(part);
    float y0 = fcb[0], y1 = fcb[1], y2 = fcb[2];
    #pragma unroll
    for (int c = 0; c < 3; ++c) {
        const int cb = c * BB + b;
        float4 t = make_float4(0.f, 0.f, 0.f, 0.f);
        #pragma unroll
        for (int sl = 0; sl < KS; ++sl) {
            float4 u = p4[(size_t)(sl * NCB + cb) * SS + s];
            t.x += u.x; t.y += u.y; t.z += u.z; t.w += u.w;
        }
        float inv = 1.0f / t.w;
        float o[3] = {t.x * inv, t.y * inv, t.z * inv};
        #pragma unroll
        for (int e = 0; e < 3; ++e) {
            float n = o[e] * sc[3 * c + e] + sh[3 * c + e];
            y0 += n * fcw[3 * c + e];
            y1 += n * fcw[9 + 3 * c + e];
            y2 += n * fcw[18 + 3 * c + e];
        }
    }
    out[r * 3 + 0] = y0;
    out[r * 3 + 1] = y1;
    out[r * 3 + 2] = y2;
}

extern "C" void kernel_launch(void* const* d_in, const int* in_sizes, int n_in,
                              void* d_out, int out_size, void* d_ws, size_t ws_size,
                              hipStream_t stream)
{
    const float* x     = (const float*)d_in[0];
    const float* WQ    = (const float*)d_in[1];
    const float* bQv   = (const float*)d_in[2];
    const float* WK    = (const float*)d_in[3];
    const float* bKv   = (const float*)d_in[4];
    const float* WV    = (const float*)d_in[5];
    const float* bVv   = (const float*)d_in[6];
    const float* gamma = (const float*)d_in[7];
    const float* beta  = (const float*)d_in[8];
    const float* fcw   = (const float*)d_in[9];
    const float* fcb   = (const float*)d_in[10];

    float* part = (float*)d_ws;                 // PART_FLOATS floats
    float* acc  = part + PART_FLOATS;           // 18 floats

    hipMemsetAsync(acc, 0, 18 * sizeof(float), stream);
    mbfca_attn<<<dim3(NCB * QCH * KS), dim3(256), 0, stream>>>(
        x, WQ, bQv, WK, bKv, WV, bVv, part);
    mbfca_stats<<<dim3(NROW / 256), dim3(256), 0, stream>>>(part, acc);
    mbfca_bnfc<<<dim3(NROW / 256), dim3(256), 0, stream>>>(
        part, acc, gamma, beta, fcw, fcb, (float*)d_out);
}

// Round 4
// 73.695 us; speedup vs baseline: 1.3039x; 1.3039x over previous
//
#include <hip/hip_runtime.h>
#include <math.h>

#define BB 48
#define SS 1024
#define NCB (3 * BB)          // 144 combo-batches
#define NROW (BB * SS)

// part[KS][NCB][SS] float4 (A0,A1,A2,l) ; acc[18] floats after it.
template <int KSv>
__global__ __launch_bounds__(256) void mbfca_attn(
    const float* __restrict__ x,
    const float* __restrict__ WQ, const float* __restrict__ bQ,
    const float* __restrict__ WK, const float* __restrict__ bK,
    const float* __restrict__ WV, const float* __restrict__ bV,
    float* __restrict__ part)
{
    constexpr int SSK = SS / KSv;        // keys per slice
    const int bid   = blockIdx.x;
    const int slice = bid % KSv;
    const int cb    = bid / KSv;         // 0..143
    const int c     = cb / BB;           // combo
    const int b     = cb % BB;           // batch
    const int kband = c;
    const int vband = (c + 1) % 3;
    const int qband = (c + 2) % 3;

    __shared__ __align__(16) float Ksm[3][SSK];
    __shared__ __align__(16) float Vsm[3][SSK];

    const int tid = threadIdx.x;

    // uniform weights
    float wk[9], wv[9], wq[9], bk[3], bv[3], bq[3];
    #pragma unroll
    for (int i = 0; i < 9; ++i) {
        wk[i] = WK[kband * 9 + i];
        wv[i] = WV[vband * 9 + i];
        wq[i] = WQ[qband * 9 + i];
    }
    #pragma unroll
    for (int i = 0; i < 3; ++i) {
        bk[i] = bK[kband * 3 + i];
        bv[i] = bV[vband * 3 + i];
        bq[i] = bQ[qband * 3 + i];
    }

    const float* xk = x + (size_t)(kband * BB + b) * SS * 3;
    const float* xv = x + (size_t)(vband * BB + b) * SS * 3;
    const float* xq = x + (size_t)(qband * BB + b) * SS * 3;

    // stage this slice's projected K,V
    for (int t = tid; t < SSK; t += 256) {
        const int tk = slice * SSK + t;
        float a0 = xk[tk * 3 + 0], a1 = xk[tk * 3 + 1], a2 = xk[tk * 3 + 2];
        Ksm[0][t] = wk[0] * a0 + wk[1] * a1 + wk[2] * a2 + bk[0];
        Ksm[1][t] = wk[3] * a0 + wk[4] * a1 + wk[5] * a2 + bk[1];
        Ksm[2][t] = wk[6] * a0 + wk[7] * a1 + wk[8] * a2 + bk[2];
        float c0 = xv[tk * 3 + 0], c1 = xv[tk * 3 + 1], c2 = xv[tk * 3 + 2];
        Vsm[0][t] = wv[0] * c0 + wv[1] * c1 + wv[2] * c2 + bv[0];
        Vsm[1][t] = wv[3] * c0 + wv[4] * c1 + wv[5] * c2 + bv[1];
        Vsm[2][t] = wv[6] * c0 + wv[7] * c1 + wv[8] * c2 + bv[2];
    }
    __syncthreads();

    // 4 queries/thread: s = 4*tid + j.
    // qscale = (1/sqrt(3)) * log2(e): v_exp_f32(q'.k) == exp(q.k/sqrt(3)).
    const float qscale = 0.57735026918962576f * 1.4426950408889634f;
    float q0[4], q1[4], q2[4];
    {
        const float4* xq4 = reinterpret_cast<const float4*>(xq + 12 * tid);
        float4 A = xq4[0], B4 = xq4[1], C4 = xq4[2];
        float a[12] = {A.x, A.y, A.z, A.w, B4.x, B4.y, B4.z, B4.w,
                       C4.x, C4.y, C4.z, C4.w};
        #pragma unroll
        for (int j = 0; j < 4; ++j) {
            float a0 = a[j * 3 + 0], a1 = a[j * 3 + 1], a2 = a[j * 3 + 2];
            q0[j] = (wq[0] * a0 + wq[1] * a1 + wq[2] * a2 + bq[0]) * qscale;
            q1[j] = (wq[3] * a0 + wq[4] * a1 + wq[5] * a2 + bq[1]) * qscale;
            q2[j] = (wq[6] * a0 + wq[7] * a1 + wq[8] * a2 + bq[2]) * qscale;
        }
    }

    float l[4]  = {0.f, 0.f, 0.f, 0.f};
    float A0[4] = {0.f, 0.f, 0.f, 0.f};
    float A1[4] = {0.f, 0.f, 0.f, 0.f};
    float A2[4] = {0.f, 0.f, 0.f, 0.f};

    const float4* K0 = reinterpret_cast<const float4*>(&Ksm[0][0]);
    const float4* K1 = reinterpret_cast<const float4*>(&Ksm[1][0]);
    const float4* K2 = reinterpret_cast<const float4*>(&Ksm[2][0]);
    const float4* V0 = reinterpret_cast<const float4*>(&Vsm[0][0]);
    const float4* V1 = reinterpret_cast<const float4*>(&Vsm[1][0]);
    const float4* V2 = reinterpret_cast<const float4*>(&Vsm[2][0]);

    for (int t4 = 0; t4 < SSK / 4; ++t4) {
        float4 k0 = K0[t4], k1 = K1[t4], k2 = K2[t4];
        float4 v0 = V0[t4], v1 = V1[t4], v2 = V2[t4];
        #pragma unroll
        for (int j = 0; j < 4; ++j) {
            float s0 = q0[j] * k0.x + q1[j] * k1.x + q2[j] * k2.x;
            float s1 = q0[j] * k0.y + q1[j] * k1.y + q2[j] * k2.y;
            float s2 = q0[j] * k0.z + q1[j] * k1.z + q2[j] * k2.z;
            float s3 = q0[j] * k0.w + q1[j] * k1.w + q2[j] * k2.w;
            float p0 = __builtin_amdgcn_exp2f(s0);   // raw v_exp_f32
            float p1 = __builtin_amdgcn_exp2f(s1);
            float p2 = __builtin_amdgcn_exp2f(s2);
            float p3 = __builtin_amdgcn_exp2f(s3);
            l[j]  += (p0 + p1) + (p2 + p3);
            A0[j] += p0 * v0.x + p1 * v0.y + p2 * v0.z + p3 * v0.w;
            A1[j] += p0 * v1.x + p1 * v1.y + p2 * v1.z + p3 * v1.w;
            A2[j] += p0 * v2.x + p1 * v2.y + p2 * v2.z + p3 * v2.w;
        }
    }

    float4* dst = reinterpret_cast<float4*>(part) +
                  ((size_t)(slice * NCB + cb) * SS + 4 * tid);
    #pragma unroll
    for (int j = 0; j < 4; ++j)
        dst[j] = make_float4(A0[j], A1[j], A2[j], l[j]);
}

// Kernel 2: reduce slices -> BN sum/sumsq partials -> 18 atomics/block.
template <int KSv>
__global__ __launch_bounds__(256) void mbfca_stats(
    const float* __restrict__ part, float* __restrict__ acc)
{
    const int r = blockIdx.x * 256 + threadIdx.x;   // row 0..49151
    const int b = r >> 10, s = r & 1023;
    __shared__ float red[4][18];

    float sums[18];
    #pragma unroll
    for (int k = 0; k < 18; ++k) sums[k] = 0.f;

    const float4* p4 = reinterpret_cast<const float4*>(part);
    #pragma unroll
    for (int c = 0; c < 3; ++c) {
        const int cb = c * BB + b;
        float4 t = make_float4(0.f, 0.f, 0.f, 0.f);
        #pragma unroll
        for (int sl = 0; sl < KSv; ++sl) {
            float4 u = p4[(size_t)(sl * NCB + cb) * SS + s];
            t.x += u.x; t.y += u.y; t.z += u.z; t.w += u.w;
        }
        float inv = 1.0f / t.w;
        float o0 = t.x * inv, o1 = t.y * inv, o2 = t.z * inv;
        sums[3 * c + 0] = o0;          sums[3 * c + 1] = o1;          sums[3 * c + 2] = o2;
        sums[9 + 3 * c + 0] = o0 * o0; sums[9 + 3 * c + 1] = o1 * o1; sums[9 + 3 * c + 2] = o2 * o2;
    }

    #pragma unroll
    for (int off = 32; off >= 1; off >>= 1)
        #pragma unroll
        for (int k = 0; k < 18; ++k)
            sums[k] += __shfl_xor(sums[k], off, 64);

    const int tid = threadIdx.x;
    if ((tid & 63) == 0) {
        #pragma unroll
        for (int k = 0; k < 18; ++k) red[tid >> 6][k] = sums[k];
    }
    __syncthreads();
    if (tid < 18)
        atomicAdd(&acc[tid], red[0][tid] + red[1][tid] + red[2][tid] + red[3][tid]);
}

// Kernel 3: re-reduce slices, apply BN + FC, write y.
template <int KSv>
__global__ __launch_bounds__(256) void mbfca_bnfc(
    const float* __restrict__ part, const float* __restrict__ acc,
    const float* __restrict__ gamma, const float* __restrict__ beta,
    const float* __restrict__ fcw, const float* __restrict__ fcb,
    float* __restrict__ out)
{
    const int r = blockIdx.x * 256 + threadIdx.x;
    const int b = r >> 10, s = r & 1023;
    const float invN = 1.0f / (float)NROW;

    float sc[9], sh[9];
    #pragma unroll
    for (int ch = 0; ch < 9; ++ch) {
        float mean = acc[ch] * invN;
        float var  = acc[9 + ch] * invN - mean * mean;  // biased variance
        float sfac = gamma[ch] * rsqrtf(var + 1e-5f);
        sc[ch] = sfac;
        sh[ch] = beta[ch] - mean * sfac;
    }

    const float4* p4 = reinterpret_cast<const float4*>(part);
    float y0 = fcb[0], y1 = fcb[1], y2 = fcb[2];
    #pragma unroll
    for (int c = 0; c < 3; ++c) {
        const int cb = c * BB + b;
        float4 t = make_float4(0.f, 0.f, 0.f, 0.f);
        #pragma unroll
        for (int sl = 0; sl < KSv; ++sl) {
            float4 u = p4[(size_t)(sl * NCB + cb) * SS + s];
            t.x += u.x; t.y += u.y; t.z += u.z; t.w += u.w;
        }
        float inv = 1.0f / t.w;
        float o[3] = {t.x * inv, t.y * inv, t.z * inv};
        #pragma unroll
        for (int e = 0; e < 3; ++e) {
            float n = o[e] * sc[3 * c + e] + sh[3 * c + e];
            y0 += n * fcw[3 * c + e];
            y1 += n * fcw[9 + 3 * c + e];
            y2 += n * fcw[18 + 3 * c + e];
        }
    }
    out[r * 3 + 0] = y0;
    out[r * 3 + 1] = y1;
    out[r * 3 + 2] = y2;
}

extern "C" void kernel_launch(void* const* d_in, const int* in_sizes, int n_in,
                              void* d_out, int out_size, void* d_ws, size_t ws_size,
                              hipStream_t stream)
{
    const float* x     = (const float*)d_in[0];
    const float* WQ    = (const float*)d_in[1];
    const float* bQv   = (const float*)d_in[2];
    const float* WK    = (const float*)d_in[3];
    const float* bKv   = (const float*)d_in[4];
    const float* WV    = (const float*)d_in[5];
    const float* bVv   = (const float*)d_in[6];
    const float* gamma = (const float*)d_in[7];
    const float* beta  = (const float*)d_in[8];
    const float* fcw   = (const float*)d_in[9];
    const float* fcb   = (const float*)d_in[10];

    float* part = (float*)d_ws;

    const size_t need8 = (size_t)8 * NCB * SS * 4 * sizeof(float) + 18 * sizeof(float);

    if (ws_size >= need8) {
        float* acc = part + (size_t)8 * NCB * SS * 4;
        hipMemsetAsync(acc, 0, 18 * sizeof(float), stream);
        mbfca_attn<8><<<dim3(NCB * 8), dim3(256), 0, stream>>>(
            x, WQ, bQv, WK, bKv, WV, bVv, part);
        mbfca_stats<8><<<dim3(NROW / 256), dim3(256), 0, stream>>>(part, acc);
        mbfca_bnfc<8><<<dim3(NROW / 256), dim3(256), 0, stream>>>(
            part, acc, gamma, beta, fcw, fcb, (float*)d_out);
    } else {
        float* acc = part + (size_t)4 * NCB * SS * 4;
        hipMemsetAsync(acc, 0, 18 * sizeof(float), stream);
        mbfca_attn<4><<<dim3(NCB * 4), dim3(256), 0, stream>>>(
            x, WQ, bQv, WK, bKv, WV, bVv, part);
        mbfca_stats<4><<<dim3(NROW / 256), dim3(256), 0, stream>>>(part, acc);
        mbfca_bnfc<4><<<dim3(NROW / 256), dim3(256), 0, stream>>>(
            part, acc, gamma, beta, fcw, fcb, (float*)d_out);
    }
}

// Round 5
// 54.265 us; speedup vs baseline: 1.7708x; 1.3581x over previous
//
#include <hip/hip_runtime.h>
#include <math.h>

#define BB 48
#define SS 1024
#define NCB (3 * BB)          // 144 combo-batches
#define NROW (BB * SS)
#define NBLK2 (NROW / 256)    // 192 epilogue blocks

typedef float f32x2 __attribute__((ext_vector_type(2)));

// ws layout: part[KS][NCB][SS] float4 (A0,A1,A2,l), then partial[NBLK2][18].
// Kernel 2 overwrites part slice 0 with o (in-place, race-free: each (cb,s)
// slot is read and written by exactly one thread).

template <int KSv>
__global__ __launch_bounds__(256) void mbfca_attn(
    const float* __restrict__ x,
    const float* __restrict__ WQ, const float* __restrict__ bQ,
    const float* __restrict__ WK, const float* __restrict__ bK,
    const float* __restrict__ WV, const float* __restrict__ bV,
    float* __restrict__ part)
{
    constexpr int SSK = SS / KSv;        // keys per slice
    const int bid   = blockIdx.x;
    const int slice = bid % KSv;
    const int cb    = bid / KSv;         // 0..143
    const int c     = cb / BB;           // combo
    const int b     = cb % BB;           // batch
    const int kband = c;
    const int vband = (c + 1) % 3;
    const int qband = (c + 2) % 3;

    __shared__ __align__(16) float Ksm[3][SSK];
    __shared__ __align__(16) float Vsm[3][SSK];

    const int tid = threadIdx.x;

    // uniform weights
    float wk[9], wv[9], wq[9], bk[3], bv[3], bq[3];
    #pragma unroll
    for (int i = 0; i < 9; ++i) {
        wk[i] = WK[kband * 9 + i];
        wv[i] = WV[vband * 9 + i];
        wq[i] = WQ[qband * 9 + i];
    }
    #pragma unroll
    for (int i = 0; i < 3; ++i) {
        bk[i] = bK[kband * 3 + i];
        bv[i] = bV[vband * 3 + i];
        bq[i] = bQ[qband * 3 + i];
    }

    const float* xk = x + (size_t)(kband * BB + b) * SS * 3;
    const float* xv = x + (size_t)(vband * BB + b) * SS * 3;
    const float* xq = x + (size_t)(qband * BB + b) * SS * 3;

    // stage this slice's projected K,V (planar)
    for (int t = tid; t < SSK; t += 256) {
        const int tk = slice * SSK + t;
        float a0 = xk[tk * 3 + 0], a1 = xk[tk * 3 + 1], a2 = xk[tk * 3 + 2];
        Ksm[0][t] = wk[0] * a0 + wk[1] * a1 + wk[2] * a2 + bk[0];
        Ksm[1][t] = wk[3] * a0 + wk[4] * a1 + wk[5] * a2 + bk[1];
        Ksm[2][t] = wk[6] * a0 + wk[7] * a1 + wk[8] * a2 + bk[2];
        float c0 = xv[tk * 3 + 0], c1 = xv[tk * 3 + 1], c2 = xv[tk * 3 + 2];
        Vsm[0][t] = wv[0] * c0 + wv[1] * c1 + wv[2] * c2 + bv[0];
        Vsm[1][t] = wv[3] * c0 + wv[4] * c1 + wv[5] * c2 + bv[1];
        Vsm[2][t] = wv[6] * c0 + wv[7] * c1 + wv[8] * c2 + bv[2];
    }
    __syncthreads();

    // 4 queries/thread, q duplicated into f32x2 pairs for packed math.
    // qscale = (1/sqrt(3)) * log2(e): v_exp_f32(q'.k) == exp(q.k/sqrt(3)).
    const float qscale = 0.57735026918962576f * 1.4426950408889634f;
    f32x2 qp0[4], qp1[4], qp2[4];
    {
        const float4* xq4 = reinterpret_cast<const float4*>(xq + 12 * tid);
        float4 A = xq4[0], B4 = xq4[1], C4 = xq4[2];
        float a[12] = {A.x, A.y, A.z, A.w, B4.x, B4.y, B4.z, B4.w,
                       C4.x, C4.y, C4.z, C4.w};
        #pragma unroll
        for (int j = 0; j < 4; ++j) {
            float a0 = a[j * 3 + 0], a1 = a[j * 3 + 1], a2 = a[j * 3 + 2];
            float t0 = (wq[0] * a0 + wq[1] * a1 + wq[2] * a2 + bq[0]) * qscale;
            float t1 = (wq[3] * a0 + wq[4] * a1 + wq[5] * a2 + bq[1]) * qscale;
            float t2 = (wq[6] * a0 + wq[7] * a1 + wq[8] * a2 + bq[2]) * qscale;
            qp0[j] = (f32x2){t0, t0};
            qp1[j] = (f32x2){t1, t1};
            qp2[j] = (f32x2){t2, t2};
        }
    }

    f32x2 lac[4], a0[4], a1[4], a2[4];
    #pragma unroll
    for (int j = 0; j < 4; ++j) {
        lac[j] = (f32x2){0.f, 0.f};
        a0[j]  = (f32x2){0.f, 0.f};
        a1[j]  = (f32x2){0.f, 0.f};
        a2[j]  = (f32x2){0.f, 0.f};
    }

    const float4* K0 = reinterpret_cast<const float4*>(&Ksm[0][0]);
    const float4* K1 = reinterpret_cast<const float4*>(&Ksm[1][0]);
    const float4* K2 = reinterpret_cast<const float4*>(&Ksm[2][0]);
    const float4* V0 = reinterpret_cast<const float4*>(&Vsm[0][0]);
    const float4* V1 = reinterpret_cast<const float4*>(&Vsm[1][0]);
    const float4* V2 = reinterpret_cast<const float4*>(&Vsm[2][0]);

    for (int t4 = 0; t4 < SSK / 4; ++t4) {
        float4 k0 = K0[t4], k1 = K1[t4], k2 = K2[t4];
        float4 v0 = V0[t4], v1 = V1[t4], v2 = V2[t4];
        f32x2 k0l = {k0.x, k0.y}, k0h = {k0.z, k0.w};
        f32x2 k1l = {k1.x, k1.y}, k1h = {k1.z, k1.w};
        f32x2 k2l = {k2.x, k2.y}, k2h = {k2.z, k2.w};
        f32x2 v0l = {v0.x, v0.y}, v0h = {v0.z, v0.w};
        f32x2 v1l = {v1.x, v1.y}, v1h = {v1.z, v1.w};
        f32x2 v2l = {v2.x, v2.y}, v2h = {v2.z, v2.w};
        #pragma unroll
        for (int j = 0; j < 4; ++j) {
            f32x2 sl = qp0[j] * k0l + qp1[j] * k1l + qp2[j] * k2l;
            f32x2 sh = qp0[j] * k0h + qp1[j] * k1h + qp2[j] * k2h;
            f32x2 pl, ph;
            pl.x = __builtin_amdgcn_exp2f(sl.x);
            pl.y = __builtin_amdgcn_exp2f(sl.y);
            ph.x = __builtin_amdgcn_exp2f(sh.x);
            ph.y = __builtin_amdgcn_exp2f(sh.y);
            lac[j] += pl + ph;
            a0[j]  += pl * v0l + ph * v0h;
            a1[j]  += pl * v1l + ph * v1h;
            a2[j]  += pl * v2l + ph * v2h;
        }
    }

    float4* dst = reinterpret_cast<float4*>(part) +
                  ((size_t)(slice * NCB + cb) * SS + 4 * tid);
    #pragma unroll
    for (int j = 0; j < 4; ++j)
        dst[j] = make_float4(a0[j].x + a0[j].y,
                             a1[j].x + a1[j].y,
                             a2[j].x + a2[j].y,
                             lac[j].x + lac[j].y);
}

// Kernel 2: reduce slices -> o (written in-place to part slice 0),
// BN sum/sumsq -> per-block partial (no atomics, no memset needed).
template <int KSv>
__global__ __launch_bounds__(256) void mbfca_stats(
    float* __restrict__ part, float* __restrict__ partial)
{
    const int r = blockIdx.x * 256 + threadIdx.x;   // row 0..49151
    const int b = r >> 10, s = r & 1023;
    __shared__ float red[4][18];

    float sums[18];
    #pragma unroll
    for (int k = 0; k < 18; ++k) sums[k] = 0.f;

    float4* p4 = reinterpret_cast<float4*>(part);
    #pragma unroll
    for (int c = 0; c < 3; ++c) {
        const int cb = c * BB + b;
        float4 t = make_float4(0.f, 0.f, 0.f, 0.f);
        #pragma unroll
        for (int sl = 0; sl < KSv; ++sl) {
            float4 u = p4[(size_t)(sl * NCB + cb) * SS + s];
            t.x += u.x; t.y += u.y; t.z += u.z; t.w += u.w;
        }
        float inv = 1.0f / t.w;
        float o0 = t.x * inv, o1 = t.y * inv, o2 = t.z * inv;
        p4[(size_t)cb * SS + s] = make_float4(o0, o1, o2, 0.f);  // in-place o
        sums[3 * c + 0] = o0;          sums[3 * c + 1] = o1;          sums[3 * c + 2] = o2;
        sums[9 + 3 * c + 0] = o0 * o0; sums[9 + 3 * c + 1] = o1 * o1; sums[9 + 3 * c + 2] = o2 * o2;
    }

    #pragma unroll
    for (int off = 32; off >= 1; off >>= 1)
        #pragma unroll
        for (int k = 0; k < 18; ++k)
            sums[k] += __shfl_xor(sums[k], off, 64);

    const int tid = threadIdx.x;
    if ((tid & 63) == 0) {
        #pragma unroll
        for (int k = 0; k < 18; ++k) red[tid >> 6][k] = sums[k];
    }
    __syncthreads();
    if (tid < 18)
        partial[blockIdx.x * 18 + tid] =
            red[0][tid] + red[1][tid] + red[2][tid] + red[3][tid];
}

// Kernel 3: reduce per-block partials -> BN scale/shift; read compact o
// from part slice 0; apply BN + FC; write y.
__global__ __launch_bounds__(256) void mbfca_bnfc(
    const float* __restrict__ part, const float* __restrict__ partial,
    const float* __restrict__ gamma, const float* __restrict__ beta,
    const float* __restrict__ fcw, const float* __restrict__ fcb,
    float* __restrict__ out)
{
    __shared__ float red[4][18];
    __shared__ float accs[18];
    const int tid = threadIdx.x;

    // reduce partial[NBLK2][18] redundantly per block (14 KB, L2-hit)
    float sums[18];
    #pragma unroll
    for (int k = 0; k < 18; ++k) sums[k] = 0.f;
    if (tid < NBLK2) {
        #pragma unroll
        for (int k = 0; k < 18; ++k) sums[k] = partial[tid * 18 + k];
    }
    #pragma unroll
    for (int off = 32; off >= 1; off >>= 1)
        #pragma unroll
        for (int k = 0; k < 18; ++k)
            sums[k] += __shfl_xor(sums[k], off, 64);
    if ((tid & 63) == 0) {
        #pragma unroll
        for (int k = 0; k < 18; ++k) red[tid >> 6][k] = sums[k];
    }
    __syncthreads();
    if (tid < 18)
        accs[tid] = red[0][tid] + red[1][tid] + red[2][tid] + red[3][tid];
    __syncthreads();

    const int r = blockIdx.x * 256 + tid;
    const int b = r >> 10, s = r & 1023;
    const float invN = 1.0f / (float)NROW;

    float sc[9], sh[9];
    #pragma unroll
    for (int ch = 0; ch < 9; ++ch) {
        float mean = accs[ch] * invN;
        float var  = accs[9 + ch] * invN - mean * mean;  // biased variance
        float sfac = gamma[ch] * rsqrtf(var + 1e-5f);
        sc[ch] = sfac;
        sh[ch] = beta[ch] - mean * sfac;
    }

    const float4* p4 = reinterpret_cast<const float4*>(part);
    float y0 = fcb[0], y1 = fcb[1], y2 = fcb[2];
    #pragma unroll
    for (int c = 0; c < 3; ++c) {
        const int cb = c * BB + b;
        float4 t = p4[(size_t)cb * SS + s];
        float o[3] = {t.x, t.y, t.z};
        #pragma unroll
        for (int e = 0; e < 3; ++e) {
            float n = o[e] * sc[3 * c + e] + sh[3 * c + e];
            y0 += n * fcw[3 * c + e];
            y1 += n * fcw[9 + 3 * c + e];
            y2 += n * fcw[18 + 3 * c + e];
        }
    }
    out[r * 3 + 0] = y0;
    out[r * 3 + 1] = y1;
    out[r * 3 + 2] = y2;
}

extern "C" void kernel_launch(void* const* d_in, const int* in_sizes, int n_in,
                              void* d_out, int out_size, void* d_ws, size_t ws_size,
                              hipStream_t stream)
{
    const float* x     = (const float*)d_in[0];
    const float* WQ    = (const float*)d_in[1];
    const float* bQv   = (const float*)d_in[2];
    const float* WK    = (const float*)d_in[3];
    const float* bKv   = (const float*)d_in[4];
    const float* WV    = (const float*)d_in[5];
    const float* bVv   = (const float*)d_in[6];
    const float* gamma = (const float*)d_in[7];
    const float* beta  = (const float*)d_in[8];
    const float* fcw   = (const float*)d_in[9];
    const float* fcb   = (const float*)d_in[10];

    float* part = (float*)d_ws;

    const size_t need8 = (size_t)8 * NCB * SS * 4 * sizeof(float)
                       + (size_t)NBLK2 * 18 * sizeof(float);

    if (ws_size >= need8) {
        float* partial = part + (size_t)8 * NCB * SS * 4;
        mbfca_attn<8><<<dim3(NCB * 8), dim3(256), 0, stream>>>(
            x, WQ, bQv, WK, bKv, WV, bVv, part);
        mbfca_stats<8><<<dim3(NBLK2), dim3(256), 0, stream>>>(part, partial);
        mbfca_bnfc<<<dim3(NBLK2), dim3(256), 0, stream>>>(
            part, partial, gamma, beta, fcw, fcb, (float*)d_out);
    } else {
        float* partial = part + (size_t)4 * NCB * SS * 4;
        mbfca_attn<4><<<dim3(NCB * 4), dim3(256), 0, stream>>>(
            x, WQ, bQv, WK, bKv, WV, bVv, part);
        mbfca_stats<4><<<dim3(NBLK2), dim3(256), 0, stream>>>(part, partial);
        mbfca_bnfc<<<dim3(NBLK2), dim3(256), 0, stream>>>(
            part, partial, gamma, beta, fcw, fcb, (float*)d_out);
    }
}

// Round 6
// 53.521 us; speedup vs baseline: 1.7954x; 1.0139x over previous
//
#include <hip/hip_runtime.h>
#include <math.h>

#define BB 48
#define SS 1024
#define NCB (3 * BB)          // 144 combo-batches
#define NROW (BB * SS)
#define NBLK2 (NROW / 256)    // 192 epilogue blocks

typedef float f32x2 __attribute__((ext_vector_type(2)));

// ws layout: part[KS][NCB][SS] float4 (A0,A1,A2,l), then partial[NBLK2][18].
// Kernel 2 overwrites part slice 0 with o (in-place, race-free: each (cb,s)
// slot is read and written by exactly one thread).

template <int KSv>
__global__ __launch_bounds__(256) void mbfca_attn(
    const float* __restrict__ x,
    const float* __restrict__ WQ, const float* __restrict__ bQ,
    const float* __restrict__ WK, const float* __restrict__ bK,
    const float* __restrict__ WV, const float* __restrict__ bV,
    float* __restrict__ part)
{
    constexpr int SSK = SS / KSv;        // keys per slice
    const int bid   = blockIdx.x;
    const int slice = bid % KSv;
    const int cb    = bid / KSv;         // 0..143
    const int c     = cb / BB;           // combo
    const int b     = cb % BB;           // batch
    const int kband = c;
    const int vband = (c + 1) % 3;
    const int qband = (c + 2) % 3;

    __shared__ __align__(16) float Ksm[3][SSK];
    __shared__ __align__(16) float Vsm[3][SSK];

    const int tid = threadIdx.x;

    // uniform weights
    float wk[9], wv[9], wq[9], bk[3], bv[3], bq[3];
    #pragma unroll
    for (int i = 0; i < 9; ++i) {
        wk[i] = WK[kband * 9 + i];
        wv[i] = WV[vband * 9 + i];
        wq[i] = WQ[qband * 9 + i];
    }
    #pragma unroll
    for (int i = 0; i < 3; ++i) {
        bk[i] = bK[kband * 3 + i];
        bv[i] = bV[vband * 3 + i];
        bq[i] = bQ[qband * 3 + i];
    }

    const float* xk = x + (size_t)(kband * BB + b) * SS * 3;
    const float* xv = x + (size_t)(vband * BB + b) * SS * 3;
    const float* xq = x + (size_t)(qband * BB + b) * SS * 3;

    // stage this slice's projected K,V (planar)
    for (int t = tid; t < SSK; t += 256) {
        const int tk = slice * SSK + t;
        float a0 = xk[tk * 3 + 0], a1 = xk[tk * 3 + 1], a2 = xk[tk * 3 + 2];
        Ksm[0][t] = wk[0] * a0 + wk[1] * a1 + wk[2] * a2 + bk[0];
        Ksm[1][t] = wk[3] * a0 + wk[4] * a1 + wk[5] * a2 + bk[1];
        Ksm[2][t] = wk[6] * a0 + wk[7] * a1 + wk[8] * a2 + bk[2];
        float c0 = xv[tk * 3 + 0], c1 = xv[tk * 3 + 1], c2 = xv[tk * 3 + 2];
        Vsm[0][t] = wv[0] * c0 + wv[1] * c1 + wv[2] * c2 + bv[0];
        Vsm[1][t] = wv[3] * c0 + wv[4] * c1 + wv[5] * c2 + bv[1];
        Vsm[2][t] = wv[6] * c0 + wv[7] * c1 + wv[8] * c2 + bv[2];
    }
    __syncthreads();

    // 4 queries/thread, q duplicated into f32x2 pairs for packed math.
    // qscale = (1/sqrt(3)) * log2(e): v_exp_f32(q'.k) == exp(q.k/sqrt(3)).
    const float qscale = 0.57735026918962576f * 1.4426950408889634f;
    f32x2 qp0[4], qp1[4], qp2[4];
    {
        const float4* xq4 = reinterpret_cast<const float4*>(xq + 12 * tid);
        float4 A = xq4[0], B4 = xq4[1], C4 = xq4[2];
        float a[12] = {A.x, A.y, A.z, A.w, B4.x, B4.y, B4.z, B4.w,
                       C4.x, C4.y, C4.z, C4.w};
        #pragma unroll
        for (int j = 0; j < 4; ++j) {
            float a0 = a[j * 3 + 0], a1 = a[j * 3 + 1], a2 = a[j * 3 + 2];
            float t0 = (wq[0] * a0 + wq[1] * a1 + wq[2] * a2 + bq[0]) * qscale;
            float t1 = (wq[3] * a0 + wq[4] * a1 + wq[5] * a2 + bq[1]) * qscale;
            float t2 = (wq[6] * a0 + wq[7] * a1 + wq[8] * a2 + bq[2]) * qscale;
            qp0[j] = (f32x2){t0, t0};
            qp1[j] = (f32x2){t1, t1};
            qp2[j] = (f32x2){t2, t2};
        }
    }

    f32x2 lac[4], a0[4], a1[4], a2[4];
    #pragma unroll
    for (int j = 0; j < 4; ++j) {
        lac[j] = (f32x2){0.f, 0.f};
        a0[j]  = (f32x2){0.f, 0.f};
        a1[j]  = (f32x2){0.f, 0.f};
        a2[j]  = (f32x2){0.f, 0.f};
    }

    const float4* K0 = reinterpret_cast<const float4*>(&Ksm[0][0]);
    const float4* K1 = reinterpret_cast<const float4*>(&Ksm[1][0]);
    const float4* K2 = reinterpret_cast<const float4*>(&Ksm[2][0]);
    const float4* V0 = reinterpret_cast<const float4*>(&Vsm[0][0]);
    const float4* V1 = reinterpret_cast<const float4*>(&Vsm[1][0]);
    const float4* V2 = reinterpret_cast<const float4*>(&Vsm[2][0]);

    for (int t4 = 0; t4 < SSK / 4; ++t4) {
        float4 k0 = K0[t4], k1 = K1[t4], k2 = K2[t4];
        float4 v0 = V0[t4], v1 = V1[t4], v2 = V2[t4];
        f32x2 k0l = {k0.x, k0.y}, k0h = {k0.z, k0.w};
        f32x2 k1l = {k1.x, k1.y}, k1h = {k1.z, k1.w};
        f32x2 k2l = {k2.x, k2.y}, k2h = {k2.z, k2.w};
        f32x2 v0l = {v0.x, v0.y}, v0h = {v0.z, v0.w};
        f32x2 v1l = {v1.x, v1.y}, v1h = {v1.z, v1.w};
        f32x2 v2l = {v2.x, v2.y}, v2h = {v2.z, v2.w};
        #pragma unroll
        for (int j = 0; j < 4; ++j) {
            f32x2 sl = qp0[j] * k0l + qp1[j] * k1l + qp2[j] * k2l;
            f32x2 sh = qp0[j] * k0h + qp1[j] * k1h + qp2[j] * k2h;
            f32x2 pl, ph;
            pl.x = __builtin_amdgcn_exp2f(sl.x);
            pl.y = __builtin_amdgcn_exp2f(sl.y);
            ph.x = __builtin_amdgcn_exp2f(sh.x);
            ph.y = __builtin_amdgcn_exp2f(sh.y);
            lac[j] += pl + ph;
            a0[j]  += pl * v0l + ph * v0h;
            a1[j]  += pl * v1l + ph * v1h;
            a2[j]  += pl * v2l + ph * v2h;
        }
    }

    float4* dst = reinterpret_cast<float4*>(part) +
                  ((size_t)(slice * NCB + cb) * SS + 4 * tid);
    #pragma unroll
    for (int j = 0; j < 4; ++j)
        dst[j] = make_float4(a0[j].x + a0[j].y,
                             a1[j].x + a1[j].y,
                             a2[j].x + a2[j].y,
                             lac[j].x + lac[j].y);
}

// Kernel 2: reduce slices -> o (written in-place to part slice 0),
// BN sum/sumsq -> per-block partial (no atomics, no memset needed).
template <int KSv>
__global__ __launch_bounds__(256) void mbfca_stats(
    float* __restrict__ part, float* __restrict__ partial)
{
    const int r = blockIdx.x * 256 + threadIdx.x;   // row 0..49151
    const int b = r >> 10, s = r & 1023;
    __shared__ float red[4][18];

    float sums[18];
    #pragma unroll
    for (int k = 0; k < 18; ++k) sums[k] = 0.f;

    float4* p4 = reinterpret_cast<float4*>(part);
    #pragma unroll
    for (int c = 0; c < 3; ++c) {
        const int cb = c * BB + b;
        float4 t = make_float4(0.f, 0.f, 0.f, 0.f);
        #pragma unroll
        for (int sl = 0; sl < KSv; ++sl) {
            float4 u = p4[(size_t)(sl * NCB + cb) * SS + s];
            t.x += u.x; t.y += u.y; t.z += u.z; t.w += u.w;
        }
        float inv = 1.0f / t.w;
        float o0 = t.x * inv, o1 = t.y * inv, o2 = t.z * inv;
        p4[(size_t)cb * SS + s] = make_float4(o0, o1, o2, 0.f);  // in-place o
        sums[3 * c + 0] = o0;          sums[3 * c + 1] = o1;          sums[3 * c + 2] = o2;
        sums[9 + 3 * c + 0] = o0 * o0; sums[9 + 3 * c + 1] = o1 * o1; sums[9 + 3 * c + 2] = o2 * o2;
    }

    #pragma unroll
    for (int off = 32; off >= 1; off >>= 1)
        #pragma unroll
        for (int k = 0; k < 18; ++k)
            sums[k] += __shfl_xor(sums[k], off, 64);

    const int tid = threadIdx.x;
    if ((tid & 63) == 0) {
        #pragma unroll
        for (int k = 0; k < 18; ++k) red[tid >> 6][k] = sums[k];
    }
    __syncthreads();
    if (tid < 18)
        partial[blockIdx.x * 18 + tid] =
            red[0][tid] + red[1][tid] + red[2][tid] + red[3][tid];
}

// Kernel 3: reduce per-block partials -> BN scale/shift; read compact o
// from part slice 0; apply BN + FC; write y.
__global__ __launch_bounds__(256) void mbfca_bnfc(
    const float* __restrict__ part, const float* __restrict__ partial,
    const float* __restrict__ gamma, const float* __restrict__ beta,
    const float* __restrict__ fcw, const float* __restrict__ fcb,
    float* __restrict__ out)
{
    __shared__ float red[4][18];
    __shared__ float accs[18];
    const int tid = threadIdx.x;

    // reduce partial[NBLK2][18] redundantly per block (14 KB, L2-hit)
    float sums[18];
    #pragma unroll
    for (int k = 0; k < 18; ++k) sums[k] = 0.f;
    if (tid < NBLK2) {
        #pragma unroll
        for (int k = 0; k < 18; ++k) sums[k] = partial[tid * 18 + k];
    }
    #pragma unroll
    for (int off = 32; off >= 1; off >>= 1)
        #pragma unroll
        for (int k = 0; k < 18; ++k)
            sums[k] += __shfl_xor(sums[k], off, 64);
    if ((tid & 63) == 0) {
        #pragma unroll
        for (int k = 0; k < 18; ++k) red[tid >> 6][k] = sums[k];
    }
    __syncthreads();
    if (tid < 18)
        accs[tid] = red[0][tid] + red[1][tid] + red[2][tid] + red[3][tid];
    __syncthreads();

    const int r = blockIdx.x * 256 + tid;
    const int b = r >> 10, s = r & 1023;
    const float invN = 1.0f / (float)NROW;

    float sc[9], sh[9];
    #pragma unroll
    for (int ch = 0; ch < 9; ++ch) {
        float mean = accs[ch] * invN;
        float var  = accs[9 + ch] * invN - mean * mean;  // biased variance
        float sfac = gamma[ch] * rsqrtf(var + 1e-5f);
        sc[ch] = sfac;
        sh[ch] = beta[ch] - mean * sfac;
    }

    const float4* p4 = reinterpret_cast<const float4*>(part);
    float y0 = fcb[0], y1 = fcb[1], y2 = fcb[2];
    #pragma unroll
    for (int c = 0; c < 3; ++c) {
        const int cb = c * BB + b;
        float4 t = p4[(size_t)cb * SS + s];
        float o[3] = {t.x, t.y, t.z};
        #pragma unroll
        for (int e = 0; e < 3; ++e) {
            float n = o[e] * sc[3 * c + e] + sh[3 * c + e];
            y0 += n * fcw[3 * c + e];
            y1 += n * fcw[9 + 3 * c + e];
            y2 += n * fcw[18 + 3 * c + e];
        }
    }
    out[r * 3 + 0] = y0;
    out[r * 3 + 1] = y1;
    out[r * 3 + 2] = y2;
}

template <int KSv>
static void run_pipeline(const float* x, const float* WQ, const float* bQ,
                         const float* WK, const float* bK,
                         const float* WV, const float* bV,
                         const float* gamma, const float* beta,
                         const float* fcw, const float* fcb,
                         float* part, float* out, hipStream_t stream)
{
    float* partial = part + (size_t)KSv * NCB * SS * 4;
    mbfca_attn<KSv><<<dim3(NCB * KSv), dim3(256), 0, stream>>>(
        x, WQ, bQ, WK, bK, WV, bV, part);
    mbfca_stats<KSv><<<dim3(NBLK2), dim3(256), 0, stream>>>(part, partial);
    mbfca_bnfc<<<dim3(NBLK2), dim3(256), 0, stream>>>(
        part, partial, gamma, beta, fcw, fcb, out);
}

extern "C" void kernel_launch(void* const* d_in, const int* in_sizes, int n_in,
                              void* d_out, int out_size, void* d_ws, size_t ws_size,
                              hipStream_t stream)
{
    const float* x     = (const float*)d_in[0];
    const float* WQ    = (const float*)d_in[1];
    const float* bQv   = (const float*)d_in[2];
    const float* WK    = (const float*)d_in[3];
    const float* bKv   = (const float*)d_in[4];
    const float* WV    = (const float*)d_in[5];
    const float* bVv   = (const float*)d_in[6];
    const float* gamma = (const float*)d_in[7];
    const float* beta  = (const float*)d_in[8];
    const float* fcw   = (const float*)d_in[9];
    const float* fcb   = (const float*)d_in[10];

    float* part = (float*)d_ws;

    const size_t tail = (size_t)NBLK2 * 18 * sizeof(float);
    const size_t need16 = (size_t)16 * NCB * SS * 4 * sizeof(float) + tail;
    const size_t need8  = (size_t)8  * NCB * SS * 4 * sizeof(float) + tail;

    if (ws_size >= need16) {
        run_pipeline<16>(x, WQ, bQv, WK, bKv, WV, bVv, gamma, beta, fcw, fcb,
                         part, (float*)d_out, stream);
    } else if (ws_size >= need8) {
        run_pipeline<8>(x, WQ, bQv, WK, bKv, WV, bVv, gamma, beta, fcw, fcb,
                        part, (float*)d_out, stream);
    } else {
        run_pipeline<4>(x, WQ, bQv, WK, bKv, WV, bVv, gamma, beta, fcw, fcb,
                        part, (float*)d_out, stream);
    }
}